// Round 1
// baseline (290.613 us; speedup 1.0000x reference)
//
#include <hip/hip_runtime.h>
#include <hip/hip_bf16.h>

#define R_CUT_F  5.0f
#define KE_F     332.0636f
#define MAX_M    1024   // harness M = 1000

__device__ __forceinline__ float softplusf(float x) {
    return logf(1.0f + expf(x));
}

// One block: prefix-scan num_atoms -> mol_starts[M+1], and zero the output.
__global__ void scan_zero_kernel(const int* __restrict__ num_atoms, int M,
                                 int* __restrict__ mol_starts,
                                 float* __restrict__ out) {
    __shared__ int buf[MAX_M];
    int t = threadIdx.x;
    buf[t] = (t < M) ? num_atoms[t] : 0;
    __syncthreads();
    // Hillis-Steele inclusive scan
    for (int off = 1; off < MAX_M; off <<= 1) {
        int x = (t >= off) ? buf[t - off] : 0;
        __syncthreads();
        buf[t] += x;
        __syncthreads();
    }
    if (t == 0) mol_starts[0] = 0;
    if (t < M) mol_starts[t + 1] = buf[t];
    for (int k = t; k < M; k += blockDim.x) out[k] = 0.0f;
}

// Block m fills mol_idx[start[m] .. end) = m. Last block extends to N
// (matches jnp.repeat total_repeat_length padding-with-last-value).
__global__ void fill_mol_kernel(const int* __restrict__ mol_starts,
                                int* __restrict__ mol_idx, int M, int N) {
    int m = blockIdx.x;
    int s = mol_starts[m];
    int e = (m == M - 1) ? N : mol_starts[m + 1];
    if (e > N) e = N;
    for (int a = s + (int)threadIdx.x; a < e; a += (int)blockDim.x)
        mol_idx[a] = m;
}

__global__ __launch_bounds__(256) void nr_main_kernel(
    const float* __restrict__ xyz, const int* __restrict__ z,
    const int* __restrict__ nbrs, const float* __restrict__ offsets,
    const int* __restrict__ mol_idx,
    const float* __restrict__ d_inv, const float* __restrict__ z_exp_inv,
    const float* __restrict__ c_inv, const float* __restrict__ exp_inv,
    float* __restrict__ out, int E, int M) {
    __shared__ float sm[MAX_M];
    for (int t = threadIdx.x; t < MAX_M; t += blockDim.x) sm[t] = 0.0f;
    __syncthreads();

    // Derived params (tiny inputs, L1-cached; amortized over ~30 edges/thread)
    const float dd    = softplusf(d_inv[0]);
    const float zexp  = softplusf(z_exp_inv[0]);
    const float c0 = softplusf(c_inv[0]);
    const float c1 = softplusf(c_inv[1]);
    const float c2 = softplusf(c_inv[2]);
    const float c3 = softplusf(c_inv[3]);
    const float e0 = softplusf(exp_inv[0]);
    const float e1 = softplusf(exp_inv[1]);
    const float e2 = softplusf(exp_inv[2]);
    const float e3 = softplusf(exp_inv[3]);
    const float inv_csum = 1.0f / (c0 + c1 + c2 + c3);
    const float inv_d    = 1.0f / dd;

    const int stride = gridDim.x * blockDim.x;
    for (int e = blockIdx.x * blockDim.x + threadIdx.x; e < E; e += stride) {
        const int2 ij = ((const int2*)nbrs)[e];
        const int i = ij.x, j = ij.y;
        if (j <= i) continue;                       // mask = j > i

        const float ox = offsets[3 * e + 0];
        const float oy = offsets[3 * e + 1];
        const float oz = offsets[3 * e + 2];
        const float dx = xyz[3 * i + 0] - xyz[3 * j + 0] - ox;
        const float dy = xyz[3 * i + 1] - xyz[3 * j + 1] - oy;
        const float dz = xyz[3 * i + 2] - xyz[3 * j + 2] - oz;
        const float r2 = dx * dx + dy * dy + dz * dz + 3e-15f;  // +3*EPS
        const float r  = sqrtf(r2);
        if (r >= R_CUT_F) continue;                 // f_cut == 0

        const float zi = (float)z[i];
        const float zj = (float)z[j];
        const float S  = __powf(zi, zexp) + __powf(zj, zexp);
        const float t  = r * S * inv_d;             // = exponents-free r/a
        const float phi = (c0 * __expf(-e0 * t) + c1 * __expf(-e1 * t) +
                           c2 * __expf(-e2 * t) + c3 * __expf(-e3 * t)) * inv_csum;
        const float fcut = __expf(-r2 / (25.0f - r2));  // den = (5-r)(5+r)
        const float val  = KE_F * zi * zj * phi * fcut / r;

        atomicAdd(&sm[mol_idx[i]], val);
    }
    __syncthreads();
    for (int t = threadIdx.x; t < M; t += blockDim.x) {
        const float v = sm[t];
        if (v != 0.0f) atomicAdd(&out[t], v);
    }
}

extern "C" void kernel_launch(void* const* d_in, const int* in_sizes, int n_in,
                              void* d_out, int out_size, void* d_ws, size_t ws_size,
                              hipStream_t stream) {
    const float* xyz       = (const float*)d_in[0];
    const int*   z         = (const int*)d_in[1];
    const int*   nbrs      = (const int*)d_in[2];
    const int*   num_atoms = (const int*)d_in[3];
    const float* offsets   = (const float*)d_in[4];
    const float* d_inv     = (const float*)d_in[5];
    const float* z_exp_inv = (const float*)d_in[6];
    const float* c_inv     = (const float*)d_in[7];
    const float* exp_inv   = (const float*)d_in[8];
    float* out = (float*)d_out;

    const int N = in_sizes[0] / 3;
    const int E = in_sizes[2] / 2;
    const int M = in_sizes[3];

    int* mol_starts = (int*)d_ws;
    int* mol_idx    = mol_starts + ((M + 1 + 3) & ~3);  // 16B-align next region

    scan_zero_kernel<<<1, MAX_M, 0, stream>>>(num_atoms, M, mol_starts, out);
    fill_mol_kernel<<<M, 64, 0, stream>>>(mol_starts, mol_idx, M, N);
    nr_main_kernel<<<1024, 256, 0, stream>>>(xyz, z, nbrs, offsets, mol_idx,
                                             d_inv, z_exp_inv, c_inv, exp_inv,
                                             out, E, M);
}

// Round 2
// 277.178 us; speedup vs baseline: 1.0485x; 1.0485x over previous
//
#include <hip/hip_runtime.h>
#include <hip/hip_bf16.h>

#define KE_F     332.0636f
#define MAX_M    1024   // padded molecule count (harness M = 1000)
#define BLK      256
#define NBLK_MAX 2048

__device__ __forceinline__ float softplusf(float x) {
    return logf(1.0f + expf(x));
}

// One block: prefix-scan num_atoms -> mol_starts[M+1], and compute the
// softplus-derived scalar constants into params[16]:
//   params[0..3] = c_k / sum(c)        (folded phi coefficients)
//   params[4..7] = exponents_k / d     (folded exponent scale; arg = -g_k * r * S)
//   params[8]    = z_exp
__global__ void scan_params_kernel(const int* __restrict__ num_atoms, int M,
                                   const float* __restrict__ d_inv,
                                   const float* __restrict__ z_exp_inv,
                                   const float* __restrict__ c_inv,
                                   const float* __restrict__ exp_inv,
                                   int* __restrict__ mol_starts,
                                   float* __restrict__ params) {
    __shared__ int buf[MAX_M];
    int t = threadIdx.x;
    buf[t] = (t < M) ? num_atoms[t] : 0;
    __syncthreads();
    for (int off = 1; off < MAX_M; off <<= 1) {   // Hillis-Steele inclusive scan
        int x = (t >= off) ? buf[t - off] : 0;
        __syncthreads();
        buf[t] += x;
        __syncthreads();
    }
    if (t == 0) mol_starts[0] = 0;
    if (t < M) mol_starts[t + 1] = buf[t];
    if (t == 0) {
        float dd = softplusf(d_inv[0]);
        float c0 = softplusf(c_inv[0]), c1 = softplusf(c_inv[1]);
        float c2 = softplusf(c_inv[2]), c3 = softplusf(c_inv[3]);
        float e0 = softplusf(exp_inv[0]), e1 = softplusf(exp_inv[1]);
        float e2 = softplusf(exp_inv[2]), e3 = softplusf(exp_inv[3]);
        float ic = 1.0f / (c0 + c1 + c2 + c3);
        float id = 1.0f / dd;
        params[0] = c0 * ic; params[1] = c1 * ic; params[2] = c2 * ic; params[3] = c3 * ic;
        params[4] = e0 * id; params[5] = e1 * id; params[6] = e2 * id; params[7] = e3 * id;
        params[8] = softplusf(z_exp_inv[0]);
    }
}

// Per-atom packing: pack[a] = (x, y, z, Zf); aux[a] = (Z^zexp, bitcast(mol)).
// mol via binary search on mol_starts (clamps to M-1, matching jnp.repeat
// total_repeat_length pad-with-last semantics).
__global__ void pack_kernel(const float* __restrict__ xyz,
                            const int* __restrict__ z,
                            const int* __restrict__ mol_starts, int M, int N,
                            const float* __restrict__ params,
                            float4* __restrict__ pack,
                            float2* __restrict__ aux) {
    int a = blockIdx.x * blockDim.x + threadIdx.x;
    if (a >= N) return;
    float zf = (float)z[a];
    pack[a] = make_float4(xyz[3 * a + 0], xyz[3 * a + 1], xyz[3 * a + 2], zf);
    int lo = 0, hi = M;                 // find lo: starts[lo] <= a < starts[lo+1]
    while (hi - lo > 1) {
        int mid = (lo + hi) >> 1;
        if (mol_starts[mid] <= a) lo = mid; else hi = mid;
    }
    aux[a] = make_float2(__powf(zf, params[8]), __int_as_float(lo));
}

__global__ __launch_bounds__(256) void nr_main_kernel(
    const long long* __restrict__ nbrs,       // int2 pairs as i64
    const float* __restrict__ offsets,
    const float4* __restrict__ pack,
    const float2* __restrict__ aux,
    const float* __restrict__ params,
    float* __restrict__ part, int E) {
    __shared__ float sm[MAX_M];
    for (int t = threadIdx.x; t < MAX_M; t += BLK) sm[t] = 0.0f;
    __syncthreads();

    const float4 kk = *(const float4*)(params + 0);   // phi coefficients
    const float4 gg = *(const float4*)(params + 4);   // exponent scales

    const int stride = gridDim.x * BLK;
    for (int e = blockIdx.x * BLK + threadIdx.x; e < E; e += stride) {
        const long long nb = __builtin_nontemporal_load(nbrs + e);
        const int i = (int)nb;
        const int j = (int)(nb >> 32);
        if (j <= i) continue;                          // mask = j > i

        const float ox = __builtin_nontemporal_load(offsets + 3 * e + 0);
        const float oy = __builtin_nontemporal_load(offsets + 3 * e + 1);
        const float oz = __builtin_nontemporal_load(offsets + 3 * e + 2);
        const float4 pi = pack[i];
        const float4 pj = pack[j];
        const float dx = pi.x - pj.x - ox;
        const float dy = pi.y - pj.y - oy;
        const float dz = pi.z - pj.z - oz;
        const float r2 = fmaf(dx, dx, fmaf(dy, dy, dz * dz)) + 3e-15f;
        if (r2 >= 25.0f) continue;                     // f_cut == 0

        const float inv_r = rsqrtf(r2);
        const float r = r2 * inv_r;
        const float2 ai = aux[i];
        const float2 aj = aux[j];
        const float rs = r * (ai.x + aj.x);            // r * (Zi^p + Zj^p); /d folded in gg
        const float phi = kk.x * __expf(-gg.x * rs) + kk.y * __expf(-gg.y * rs) +
                          kk.z * __expf(-gg.z * rs) + kk.w * __expf(-gg.w * rs);
        const float fcut = __expf(-__fdividef(r2, 25.0f - r2));
        const float val = KE_F * pi.w * pj.w * inv_r * phi * fcut;

        atomicAdd(&sm[__float_as_int(ai.y)], val);
    }
    __syncthreads();
    // Coalesced flush of the per-block histogram: one float4 per thread.
    const float4* sm4 = (const float4*)sm;
    float4* dst = (float4*)(part + (size_t)blockIdx.x * MAX_M);
    dst[threadIdx.x] = sm4[threadIdx.x];
}

// Block q reduces molecules 4q..4q+3 across nblk partial histograms.
__global__ void reduce_kernel(const float* __restrict__ part, int nblk,
                              float* __restrict__ out, int M) {
    __shared__ float4 smr[BLK];
    const int q = blockIdx.x;
    float4 acc = make_float4(0.f, 0.f, 0.f, 0.f);
    for (int b = threadIdx.x; b < nblk; b += BLK) {
        const float4 v = *(const float4*)(part + (size_t)b * MAX_M + 4 * q);
        acc.x += v.x; acc.y += v.y; acc.z += v.z; acc.w += v.w;
    }
    smr[threadIdx.x] = acc;
    __syncthreads();
    for (int s = BLK / 2; s > 0; s >>= 1) {
        if (threadIdx.x < s) {
            smr[threadIdx.x].x += smr[threadIdx.x + s].x;
            smr[threadIdx.x].y += smr[threadIdx.x + s].y;
            smr[threadIdx.x].z += smr[threadIdx.x + s].z;
            smr[threadIdx.x].w += smr[threadIdx.x + s].w;
        }
        __syncthreads();
    }
    if (threadIdx.x == 0) {
        const int m = 4 * q;
        const float4 r = smr[0];
        if (m + 0 < M) out[m + 0] = r.x;
        if (m + 1 < M) out[m + 1] = r.y;
        if (m + 2 < M) out[m + 2] = r.z;
        if (m + 3 < M) out[m + 3] = r.w;
    }
}

extern "C" void kernel_launch(void* const* d_in, const int* in_sizes, int n_in,
                              void* d_out, int out_size, void* d_ws, size_t ws_size,
                              hipStream_t stream) {
    const float* xyz       = (const float*)d_in[0];
    const int*   z         = (const int*)d_in[1];
    const int*   nbrs      = (const int*)d_in[2];
    const int*   num_atoms = (const int*)d_in[3];
    const float* offsets   = (const float*)d_in[4];
    const float* d_inv     = (const float*)d_in[5];
    const float* z_exp_inv = (const float*)d_in[6];
    const float* c_inv     = (const float*)d_in[7];
    const float* exp_inv   = (const float*)d_in[8];
    float* out = (float*)d_out;

    const int N = in_sizes[0] / 3;
    const int E = in_sizes[2] / 2;
    const int M = in_sizes[3];

    // Workspace layout (16B-aligned regions):
    //   [0, 4096)                : mol_starts (M+1 ints)
    //   [4096, 8192)             : params (16 floats)
    //   [8192, 8192+16N)         : pack  (N float4)
    //   [.., +8N)                : aux   (N float2)
    //   [.., +4*MAX_M*nblk)      : part  (per-block histograms)
    char* w = (char*)d_ws;
    int*    mol_starts = (int*)w;
    float*  params     = (float*)(w + 4096);
    float4* pack       = (float4*)(w + 8192);
    float2* aux        = (float2*)(w + 8192 + 16 * (size_t)N);
    size_t  part_off   = 8192 + 24 * (size_t)N;
    float*  part       = (float*)(w + part_off);

    int nblk = NBLK_MAX;
    if (ws_size > part_off) {
        size_t maxb = (ws_size - part_off) / (sizeof(float) * MAX_M);
        if ((size_t)nblk > maxb) nblk = (int)maxb;
    } else {
        nblk = 1;  // degenerate fallback; assumes generous ws in practice
    }
    if (nblk < 1) nblk = 1;

    scan_params_kernel<<<1, MAX_M, 0, stream>>>(num_atoms, M, d_inv, z_exp_inv,
                                                c_inv, exp_inv, mol_starts, params);
    pack_kernel<<<(N + BLK - 1) / BLK, BLK, 0, stream>>>(xyz, z, mol_starts, M, N,
                                                         params, pack, aux);
    nr_main_kernel<<<nblk, BLK, 0, stream>>>((const long long*)nbrs, offsets,
                                             pack, aux, params, part, E);
    reduce_kernel<<<(M + 3) / 4, BLK, 0, stream>>>(part, nblk, out, M);
}

// Round 4
// 260.770 us; speedup vs baseline: 1.1144x; 1.0629x over previous
//
#include <hip/hip_runtime.h>
#include <hip/hip_bf16.h>

#define KE_F  332.0636f
#define MAX_M 1024   // padded molecule count (harness M = 1000)
#define BLK   256
#define NBLK  2048

typedef int   ivec4 __attribute__((ext_vector_type(4)));
typedef float fvec4 __attribute__((ext_vector_type(4)));

__device__ __forceinline__ float softplusf(float x) {
    return logf(1.0f + expf(x));
}

// One block: prefix-scan num_atoms -> mol_starts[M+1]; derived constants into
// params: [0..3]=c_k/sum(c), [4..7]=exponents_k/d, [16..111]=Z^zexp table;
// also zeroes out[0..M) (harness re-poisons d_out to 0xAA each launch).
__global__ void scan_params_kernel(const int* __restrict__ num_atoms, int M,
                                   const float* __restrict__ d_inv,
                                   const float* __restrict__ z_exp_inv,
                                   const float* __restrict__ c_inv,
                                   const float* __restrict__ exp_inv,
                                   int* __restrict__ mol_starts,
                                   float* __restrict__ params,
                                   float* __restrict__ out) {
    __shared__ int buf[MAX_M];
    int t = threadIdx.x;
    buf[t] = (t < M) ? num_atoms[t] : 0;
    __syncthreads();
    for (int off = 1; off < MAX_M; off <<= 1) {   // Hillis-Steele inclusive scan
        int x = (t >= off) ? buf[t - off] : 0;
        __syncthreads();
        buf[t] += x;
        __syncthreads();
    }
    if (t == 0) mol_starts[0] = 0;
    if (t < M) mol_starts[t + 1] = buf[t];
    if (t == 0) {
        float dd = softplusf(d_inv[0]);
        float c0 = softplusf(c_inv[0]), c1 = softplusf(c_inv[1]);
        float c2 = softplusf(c_inv[2]), c3 = softplusf(c_inv[3]);
        float e0 = softplusf(exp_inv[0]), e1 = softplusf(exp_inv[1]);
        float e2 = softplusf(exp_inv[2]), e3 = softplusf(exp_inv[3]);
        float ic = 1.0f / (c0 + c1 + c2 + c3);
        float id = 1.0f / dd;
        params[0] = c0 * ic; params[1] = c1 * ic; params[2] = c2 * ic; params[3] = c3 * ic;
        params[4] = e0 * id; params[5] = e1 * id; params[6] = e2 * id; params[7] = e3 * id;
    }
    if (t < 96) {                                  // z in [1,94): table of Z^zexp
        float zexp = softplusf(z_exp_inv[0]);
        params[16 + t] = __powf((float)t, zexp);
    }
    for (int k = t; k < M; k += MAX_M) out[k] = 0.0f;
}

// Per-atom packing: pack[a] = (x,y,z,Zf); mol[a] via binary search on
// mol_starts (clamps to M-1, matching jnp.repeat total_repeat_length pad).
__global__ void pack_kernel(const float* __restrict__ xyz,
                            const int* __restrict__ z,
                            const int* __restrict__ mol_starts, int M, int N,
                            float4* __restrict__ pack, int* __restrict__ mol) {
    int a = blockIdx.x * blockDim.x + threadIdx.x;
    if (a >= N) return;
    pack[a] = make_float4(xyz[3 * a + 0], xyz[3 * a + 1], xyz[3 * a + 2],
                          (float)z[a]);
    int lo = 0, hi = M;
    while (hi - lo > 1) {
        int mid = (lo + hi) >> 1;
        if (mol_starts[mid] <= a) lo = mid; else hi = mid;
    }
    mol[a] = lo;
}

__global__ __launch_bounds__(BLK) void nr_main_kernel(
    const int* __restrict__ nbrs, const float* __restrict__ offsets,
    const float4* __restrict__ pack, const int* __restrict__ mol,
    const float* __restrict__ params, float* __restrict__ out, int E, int M) {
    __shared__ float sm[MAX_M];
    __shared__ float zp[96];
    for (int t = threadIdx.x; t < MAX_M; t += BLK) sm[t] = 0.0f;
    if (threadIdx.x < 96) zp[threadIdx.x] = params[16 + threadIdx.x];
    __syncthreads();

    const float4 kk = *(const float4*)(params + 0);   // phi coefficients
    const float4 gg = *(const float4*)(params + 4);   // exponent scales (/d folded)

    const int ngroups = E >> 2;                       // 4 edges per group
    const int stride = gridDim.x * BLK;
    const ivec4* nb4 = (const ivec4*)nbrs;
    const fvec4* of4 = (const fvec4*)offsets;

    for (int g = blockIdx.x * BLK + threadIdx.x; g < ngroups; g += stride) {
        // Coalesced streaming loads: 2x int4 (4 edges) + 3x float4 (12 floats).
        const ivec4 n01 = __builtin_nontemporal_load(nb4 + 2 * (size_t)g);
        const ivec4 n23 = __builtin_nontemporal_load(nb4 + 2 * (size_t)g + 1);
        const fvec4 oA  = __builtin_nontemporal_load(of4 + 3 * (size_t)g);
        const fvec4 oB  = __builtin_nontemporal_load(of4 + 3 * (size_t)g + 1);
        const fvec4 oC  = __builtin_nontemporal_load(of4 + 3 * (size_t)g + 2);

        const int   iv[4] = {n01.x, n01.z, n23.x, n23.z};
        const int   jv[4] = {n01.y, n01.w, n23.y, n23.w};
        const float ox[4] = {oA.x, oA.w, oB.z, oC.y};
        const float oy[4] = {oA.y, oB.x, oB.w, oC.z};
        const float oz[4] = {oA.z, oB.y, oC.x, oC.w};

        bool   m[4];
        float4 pi[4], pj[4];
        int    mi[4];
#pragma unroll
        for (int k = 0; k < 4; ++k) {    // issue ALL gathers batched, branch-free
            m[k] = jv[k] > iv[k];
            const int ii = m[k] ? iv[k] : 0;   // masked lanes broadcast line 0
            const int jj = m[k] ? jv[k] : 0;
            pi[k] = pack[ii];
            pj[k] = pack[jj];
            mi[k] = mol[ii];
        }
#pragma unroll
        for (int k = 0; k < 4; ++k) {
            const float dx = pi[k].x - pj[k].x - ox[k];
            const float dy = pi[k].y - pj[k].y - oy[k];
            const float dz = pi[k].z - pj[k].z - oz[k];
            const float r2 = fmaf(dx, dx, fmaf(dy, dy, dz * dz)) + 3e-15f;
            const bool ok = m[k] && (r2 < 25.0f);
            const float inv_r = rsqrtf(r2);
            const float r = r2 * inv_r;
            const float S = zp[(int)pi[k].w] + zp[(int)pj[k].w];
            const float rs = r * S;
            const float phi = kk.x * __expf(-gg.x * rs) + kk.y * __expf(-gg.y * rs) +
                              kk.z * __expf(-gg.z * rs) + kk.w * __expf(-gg.w * rs);
            const float fc = __expf(-__fdividef(r2, 25.0f - r2));
            const float val = KE_F * pi[k].w * pj[k].w * inv_r * phi * fc;
            if (ok) atomicAdd(&sm[mi[k]], val);   // inf/nan of masked lanes discarded
        }
    }

    // Tail edges [4*ngroups, E) — scalar path (E%4, usually empty).
    for (int e = (ngroups << 2) + blockIdx.x * BLK + threadIdx.x; e < E; e += stride) {
        const int i = nbrs[2 * e], j = nbrs[2 * e + 1];
        if (j <= i) continue;
        const float oxs = offsets[3 * e], oys = offsets[3 * e + 1], ozs = offsets[3 * e + 2];
        const float4 pis = pack[i], pjs = pack[j];
        const float dx = pis.x - pjs.x - oxs;
        const float dy = pis.y - pjs.y - oys;
        const float dz = pis.z - pjs.z - ozs;
        const float r2 = fmaf(dx, dx, fmaf(dy, dy, dz * dz)) + 3e-15f;
        if (r2 >= 25.0f) continue;
        const float inv_r = rsqrtf(r2);
        const float r = r2 * inv_r;
        const float S = zp[(int)pis.w] + zp[(int)pjs.w];
        const float rs = r * S;
        const float phi = kk.x * __expf(-gg.x * rs) + kk.y * __expf(-gg.y * rs) +
                          kk.z * __expf(-gg.z * rs) + kk.w * __expf(-gg.w * rs);
        const float fc = __expf(-__fdividef(r2, 25.0f - r2));
        atomicAdd(&sm[mol[i]], KE_F * pis.w * pjs.w * inv_r * phi * fc);
    }

    __syncthreads();
    // Sparse flush: ~35% of slots nonzero per block -> ~0.7M global atomics total.
    for (int t = threadIdx.x; t < M; t += BLK) {
        const float v = sm[t];
        if (v != 0.0f) atomicAdd(&out[t], v);
    }
}

extern "C" void kernel_launch(void* const* d_in, const int* in_sizes, int n_in,
                              void* d_out, int out_size, void* d_ws, size_t ws_size,
                              hipStream_t stream) {
    const float* xyz       = (const float*)d_in[0];
    const int*   z         = (const int*)d_in[1];
    const int*   nbrs      = (const int*)d_in[2];
    const int*   num_atoms = (const int*)d_in[3];
    const float* offsets   = (const float*)d_in[4];
    const float* d_inv     = (const float*)d_in[5];
    const float* z_exp_inv = (const float*)d_in[6];
    const float* c_inv     = (const float*)d_in[7];
    const float* exp_inv   = (const float*)d_in[8];
    float* out = (float*)d_out;

    const int N = in_sizes[0] / 3;
    const int E = in_sizes[2] / 2;
    const int M = in_sizes[3];

    // Workspace layout (16B-aligned regions):
    //   [0, 4096)            : mol_starts (M+1 ints)
    //   [4096, 8192)         : params (112 floats used)
    //   [8192, 8192+16N)     : pack (N float4)
    //   [.., +4N)            : mol  (N int)
    char* w = (char*)d_ws;
    int*    mol_starts = (int*)w;
    float*  params     = (float*)(w + 4096);
    float4* pack       = (float4*)(w + 8192);
    int*    mol        = (int*)(w + 8192 + 16 * (size_t)N);

    scan_params_kernel<<<1, MAX_M, 0, stream>>>(num_atoms, M, d_inv, z_exp_inv,
                                                c_inv, exp_inv, mol_starts,
                                                params, out);
    pack_kernel<<<(N + BLK - 1) / BLK, BLK, 0, stream>>>(xyz, z, mol_starts, M, N,
                                                         pack, mol);
    nr_main_kernel<<<NBLK, BLK, 0, stream>>>(nbrs, offsets, pack, mol,
                                             params, out, E, M);
}

// Round 5
// 246.674 us; speedup vs baseline: 1.1781x; 1.0571x over previous
//
#include <hip/hip_runtime.h>
#include <hip/hip_bf16.h>

#define KE_F  332.0636f
#define MAX_M 1024   // padded molecule count (harness M = 1000)
#define BLK   256
#define NBLK  2048

typedef int   ivec4 __attribute__((ext_vector_type(4)));
typedef float fvec4 __attribute__((ext_vector_type(4)));

__device__ __forceinline__ float softplusf(float x) {
    return logf(1.0f + expf(x));
}

// One block: prefix-scan num_atoms -> mol_starts[M+1]; derived constants into
// params: [0..3]=c_k/sum(c), [4..7]=exponents_k/d, [16..111]=Z^zexp table;
// also zeroes out[0..M) (harness re-poisons d_out to 0xAA each launch).
__global__ void scan_params_kernel(const int* __restrict__ num_atoms, int M,
                                   const float* __restrict__ d_inv,
                                   const float* __restrict__ z_exp_inv,
                                   const float* __restrict__ c_inv,
                                   const float* __restrict__ exp_inv,
                                   int* __restrict__ mol_starts,
                                   float* __restrict__ params,
                                   float* __restrict__ out) {
    __shared__ int buf[MAX_M];
    int t = threadIdx.x;
    buf[t] = (t < M) ? num_atoms[t] : 0;
    __syncthreads();
    for (int off = 1; off < MAX_M; off <<= 1) {   // Hillis-Steele inclusive scan
        int x = (t >= off) ? buf[t - off] : 0;
        __syncthreads();
        buf[t] += x;
        __syncthreads();
    }
    if (t == 0) mol_starts[0] = 0;
    if (t < M) mol_starts[t + 1] = buf[t];
    if (t == 0) {
        float dd = softplusf(d_inv[0]);
        float c0 = softplusf(c_inv[0]), c1 = softplusf(c_inv[1]);
        float c2 = softplusf(c_inv[2]), c3 = softplusf(c_inv[3]);
        float e0 = softplusf(exp_inv[0]), e1 = softplusf(exp_inv[1]);
        float e2 = softplusf(exp_inv[2]), e3 = softplusf(exp_inv[3]);
        float ic = 1.0f / (c0 + c1 + c2 + c3);
        float id = 1.0f / dd;
        params[0] = c0 * ic; params[1] = c1 * ic; params[2] = c2 * ic; params[3] = c3 * ic;
        params[4] = e0 * id; params[5] = e1 * id; params[6] = e2 * id; params[7] = e3 * id;
    }
    if (t < 96) {                                  // z in [1,94): table of Z^zexp
        float zexp = softplusf(z_exp_inv[0]);
        params[16 + t] = __powf((float)t, zexp);
    }
    for (int k = t; k < M; k += MAX_M) out[k] = 0.0f;
}

// Per-atom packing: pack[a] = (x, y, z, encode(mol, Z)) where
// encode = float((mol << 7) | Z)  (exact: < 2^17). mol via binary search on
// mol_starts (clamps to M-1, matching jnp.repeat total_repeat_length pad).
__global__ void pack_kernel(const float* __restrict__ xyz,
                            const int* __restrict__ z,
                            const int* __restrict__ mol_starts, int M, int N,
                            float4* __restrict__ pack) {
    int a = blockIdx.x * blockDim.x + threadIdx.x;
    if (a >= N) return;
    int lo = 0, hi = M;
    while (hi - lo > 1) {
        int mid = (lo + hi) >> 1;
        if (mol_starts[mid] <= a) lo = mid; else hi = mid;
    }
    pack[a] = make_float4(xyz[3 * a + 0], xyz[3 * a + 1], xyz[3 * a + 2],
                          (float)((lo << 7) | z[a]));
}

__global__ __launch_bounds__(BLK) void nr_main_kernel(
    const int* __restrict__ nbrs, const float* __restrict__ offsets,
    const float4* __restrict__ pack,
    const float* __restrict__ params, float* __restrict__ out, int E, int M) {
    __shared__ float sm[MAX_M];
    __shared__ float zp[96];
    for (int t = threadIdx.x; t < MAX_M; t += BLK) sm[t] = 0.0f;
    if (threadIdx.x < 96) zp[threadIdx.x] = params[16 + threadIdx.x];
    __syncthreads();

    const float4 kk = *(const float4*)(params + 0);   // phi coefficients
    const float4 gg = *(const float4*)(params + 4);   // exponent scales (/d folded)

    const int ngroups = E >> 2;                       // 4 edges per group
    const int stride = gridDim.x * BLK;
    const ivec4* nb4 = (const ivec4*)nbrs;
    const fvec4* of4 = (const fvec4*)offsets;

    for (int g = blockIdx.x * BLK + threadIdx.x; g < ngroups; g += stride) {
        // Coalesced streaming loads: 2x int4 (4 edges) + 3x float4 (12 floats).
        const ivec4 n01 = __builtin_nontemporal_load(nb4 + 2 * (size_t)g);
        const ivec4 n23 = __builtin_nontemporal_load(nb4 + 2 * (size_t)g + 1);
        const fvec4 oA  = __builtin_nontemporal_load(of4 + 3 * (size_t)g);
        const fvec4 oB  = __builtin_nontemporal_load(of4 + 3 * (size_t)g + 1);
        const fvec4 oC  = __builtin_nontemporal_load(of4 + 3 * (size_t)g + 2);

        const int   iv[4] = {n01.x, n01.z, n23.x, n23.z};
        const int   jv[4] = {n01.y, n01.w, n23.y, n23.w};
        const float ox[4] = {oA.x, oA.w, oB.z, oC.y};
        const float oy[4] = {oA.y, oB.x, oB.w, oC.z};
        const float oz[4] = {oA.z, oB.y, oC.x, oC.w};

        bool   m[4];
        float4 pi[4], pj[4];
#pragma unroll
        for (int k = 0; k < 4; ++k) {    // issue ALL gathers batched, branch-free
            m[k] = jv[k] > iv[k];
            const int ii = m[k] ? iv[k] : 0;   // masked lanes broadcast line 0
            const int jj = m[k] ? jv[k] : 0;
            pi[k] = pack[ii];
            pj[k] = pack[jj];
        }
#pragma unroll
        for (int k = 0; k < 4; ++k) {
            const float dx = pi[k].x - pj[k].x - ox[k];
            const float dy = pi[k].y - pj[k].y - oy[k];
            const float dz = pi[k].z - pj[k].z - oz[k];
            const float r2 = fmaf(dx, dx, fmaf(dy, dy, dz * dz)) + 3e-15f;
            const bool ok = m[k] && (r2 < 25.0f);
            const int  wi = (int)pi[k].w;
            const int  wj = (int)pj[k].w;
            const float zi = (float)(wi & 127);
            const float zj = (float)(wj & 127);
            const float inv_r = rsqrtf(r2);
            const float r = r2 * inv_r;
            const float S = zp[wi & 127] + zp[wj & 127];
            const float rs = r * S;
            const float phi = kk.x * __expf(-gg.x * rs) + kk.y * __expf(-gg.y * rs) +
                              kk.z * __expf(-gg.z * rs) + kk.w * __expf(-gg.w * rs);
            const float fc = __expf(-__fdividef(r2, 25.0f - r2));
            const float val = KE_F * zi * zj * inv_r * phi * fc;
            if (ok) atomicAdd(&sm[wi >> 7], val);   // inf/nan of masked lanes discarded
        }
    }

    // Tail edges [4*ngroups, E) — scalar path (E%4, usually empty).
    for (int e = (ngroups << 2) + blockIdx.x * BLK + threadIdx.x; e < E; e += stride) {
        const int i = nbrs[2 * e], j = nbrs[2 * e + 1];
        if (j <= i) continue;
        const float oxs = offsets[3 * e], oys = offsets[3 * e + 1], ozs = offsets[3 * e + 2];
        const float4 pis = pack[i], pjs = pack[j];
        const float dx = pis.x - pjs.x - oxs;
        const float dy = pis.y - pjs.y - oys;
        const float dz = pis.z - pjs.z - ozs;
        const float r2 = fmaf(dx, dx, fmaf(dy, dy, dz * dz)) + 3e-15f;
        if (r2 >= 25.0f) continue;
        const int  wi = (int)pis.w;
        const int  wj = (int)pjs.w;
        const float inv_r = rsqrtf(r2);
        const float r = r2 * inv_r;
        const float S = zp[wi & 127] + zp[wj & 127];
        const float rs = r * S;
        const float phi = kk.x * __expf(-gg.x * rs) + kk.y * __expf(-gg.y * rs) +
                          kk.z * __expf(-gg.z * rs) + kk.w * __expf(-gg.w * rs);
        const float fc = __expf(-__fdividef(r2, 25.0f - r2));
        atomicAdd(&sm[wi >> 7],
                  KE_F * (float)(wi & 127) * (float)(wj & 127) * inv_r * phi * fc);
    }

    __syncthreads();
    // Sparse flush: ~35% of slots nonzero per block -> ~0.7M global atomics total.
    for (int t = threadIdx.x; t < M; t += BLK) {
        const float v = sm[t];
        if (v != 0.0f) atomicAdd(&out[t], v);
    }
}

extern "C" void kernel_launch(void* const* d_in, const int* in_sizes, int n_in,
                              void* d_out, int out_size, void* d_ws, size_t ws_size,
                              hipStream_t stream) {
    const float* xyz       = (const float*)d_in[0];
    const int*   z         = (const int*)d_in[1];
    const int*   nbrs      = (const int*)d_in[2];
    const int*   num_atoms = (const int*)d_in[3];
    const float* offsets   = (const float*)d_in[4];
    const float* d_inv     = (const float*)d_in[5];
    const float* z_exp_inv = (const float*)d_in[6];
    const float* c_inv     = (const float*)d_in[7];
    const float* exp_inv   = (const float*)d_in[8];
    float* out = (float*)d_out;

    const int N = in_sizes[0] / 3;
    const int E = in_sizes[2] / 2;
    const int M = in_sizes[3];

    // Workspace layout (16B-aligned regions):
    //   [0, 4096)            : mol_starts (M+1 ints)
    //   [4096, 8192)         : params (112 floats used)
    //   [8192, 8192+16N)     : pack (N float4; w = (mol<<7)|Z encoded)
    char* w = (char*)d_ws;
    int*    mol_starts = (int*)w;
    float*  params     = (float*)(w + 4096);
    float4* pack       = (float4*)(w + 8192);

    scan_params_kernel<<<1, MAX_M, 0, stream>>>(num_atoms, M, d_inv, z_exp_inv,
                                                c_inv, exp_inv, mol_starts,
                                                params, out);
    pack_kernel<<<(N + BLK - 1) / BLK, BLK, 0, stream>>>(xyz, z, mol_starts, M, N,
                                                         pack);
    nr_main_kernel<<<NBLK, BLK, 0, stream>>>(nbrs, offsets, pack,
                                             params, out, E, M);
}